// Round 1
// baseline (561.996 us; speedup 1.0000x reference)
//
#include <hip/hip_runtime.h>
#include <math.h>

#define D    1024
#define C    16
#define N    256
#define TOK  8192   // B*S = 4*2048
#define DH   512    // D/2

__device__ __forceinline__ float gelu_exact(float v) {
    return 0.5f * v * (1.0f + erff(v * 0.70710678118654752440f));
}

__device__ __forceinline__ float sigmoidf_(float z) {
    return 1.0f / (1.0f + expf(-z));
}

// ---------------------------------------------------------------------------
// prep: col_emb norms + zero routing counters
// ---------------------------------------------------------------------------
__global__ void prep_kernel(const float* __restrict__ col_emb, float* __restrict__ cnorm,
                            int* __restrict__ counts, int* __restrict__ cursor) {
    const int tid = threadIdx.x;              // 256
    const int c = tid >> 4, l = tid & 15;
    float acc = 0.f;
    for (int j = 0; j < 64; ++j) {
        float v = col_emb[c * D + l + 16 * j];
        acc += v * v;
    }
    for (int off = 8; off; off >>= 1) acc += __shfl_xor(acc, off, 16);
    if (l == 0) cnorm[c] = fmaxf(sqrtf(acc), 1e-12f);
    if (tid < C) { counts[tid] = 0; cursor[tid] = 0; }
}

// ---------------------------------------------------------------------------
// gate GEMM1: H = gelu(x @ gate_w1 + b1)   [8192,1024] x [1024,512]
// 64x64 tile, BK=32, 256 threads, 4x4 per thread
// ---------------------------------------------------------------------------
__global__ __launch_bounds__(256) void gate_gemm_kernel(
        const float* __restrict__ x, const float* __restrict__ w1,
        const float* __restrict__ b1, float* __restrict__ H) {
    __shared__ float Ast[32][64];   // transposed A: [k][m]
    __shared__ float Bs[32][64];    // [k][n]
    const int tid = threadIdx.x;
    const int tn = tid & 15, tm = tid >> 4;          // 16 x 16 thread grid
    const int mBase = blockIdx.x * 64, nBase = blockIdx.y * 64;
    const int am = tid >> 2, akq = tid & 3;          // A staging
    const int br = tid >> 3, bcq = tid & 7;          // B staging
    float acc[4][4] = {};
    for (int kk = 0; kk < D; kk += 32) {
        #pragma unroll
        for (int h = 0; h < 2; ++h) {
            const int kq = akq + 4 * h;              // 0..7
            const float4 v = *(const float4*)&x[(size_t)(mBase + am) * D + kk + kq * 4];
            Ast[kq * 4 + 0][am] = v.x; Ast[kq * 4 + 1][am] = v.y;
            Ast[kq * 4 + 2][am] = v.z; Ast[kq * 4 + 3][am] = v.w;
        }
        #pragma unroll
        for (int h = 0; h < 2; ++h) {
            const int cq = bcq + 8 * h;              // 0..15
            *(float4*)&Bs[br][cq * 4] =
                *(const float4*)&w1[(size_t)(kk + br) * DH + nBase + cq * 4];
        }
        __syncthreads();
        #pragma unroll
        for (int k = 0; k < 32; ++k) {
            const float4 a4 = *(const float4*)&Ast[k][tm * 4];
            const float4 b4 = *(const float4*)&Bs[k][tn * 4];
            const float av[4] = {a4.x, a4.y, a4.z, a4.w};
            const float bv[4] = {b4.x, b4.y, b4.z, b4.w};
            #pragma unroll
            for (int i = 0; i < 4; ++i)
                #pragma unroll
                for (int j = 0; j < 4; ++j)
                    acc[i][j] = fmaf(av[i], bv[j], acc[i][j]);
        }
        __syncthreads();
    }
    const int n = nBase + tn * 4;
    const float4 bb = *(const float4*)&b1[n];
    #pragma unroll
    for (int i = 0; i < 4; ++i) {
        const int m = mBase + tm * 4 + i;
        float4 o;
        o.x = gelu_exact(acc[i][0] + bb.x);
        o.y = gelu_exact(acc[i][1] + bb.y);
        o.z = gelu_exact(acc[i][2] + bb.z);
        o.w = gelu_exact(acc[i][3] + bb.w);
        *(float4*)&H[(size_t)m * DH + n] = o;
    }
}

// ---------------------------------------------------------------------------
// route: logits = sim + sigmoid(H @ gate_w2 + b2); top-1 idx + softmax weight
// one block handles 16 tokens serially
// ---------------------------------------------------------------------------
__global__ __launch_bounds__(256) void route_kernel(
        const float* __restrict__ x, const float* __restrict__ H,
        const float* __restrict__ col_emb, const float* __restrict__ cnorm,
        const float* __restrict__ w2, const float* __restrict__ b2,
        int* __restrict__ idx, float* __restrict__ wgt, int* __restrict__ counts) {
    __shared__ float xl[D];
    __shared__ float hl[DH];
    __shared__ float simArr[C];
    __shared__ float red[16][17];
    __shared__ float logitArr[C];
    __shared__ float wavered[4];
    const int tid = threadIdx.x;
    const int c = tid >> 4, l16 = tid & 15;
    for (int ti = 0; ti < 16; ++ti) {
        const int t = blockIdx.x * 16 + ti;
        const float4 xv = *(const float4*)&x[(size_t)t * D + tid * 4];
        *(float4*)&xl[tid * 4] = xv;
        float ss = xv.x * xv.x + xv.y * xv.y + xv.z * xv.z + xv.w * xv.w;
        for (int off = 32; off; off >>= 1) ss += __shfl_xor(ss, off);
        if ((tid & 63) == 0) wavered[tid >> 6] = ss;
        if (tid < 128)
            *(float4*)&hl[tid * 4] = *(const float4*)&H[(size_t)t * DH + tid * 4];
        __syncthreads();
        const float xn = fmaxf(sqrtf(wavered[0] + wavered[1] + wavered[2] + wavered[3]), 1e-12f);
        // similarity: 16 lanes per column
        float sacc = 0.f;
        for (int j = 0; j < 64; ++j) {
            const int d = l16 + 16 * j;
            sacc += xl[d] * col_emb[c * D + d];
        }
        for (int off = 8; off; off >>= 1) sacc += __shfl_xor(sacc, off, 16);
        if (l16 == 0) simArr[c] = sacc / (xn * cnorm[c]);
        // gate2: 16 partials x 16 columns
        const int cc = tid & 15, part = tid >> 4;
        float g = 0.f;
        for (int i = 0; i < 32; ++i) {
            const int d = part * 32 + i;
            g += hl[d] * w2[d * C + cc];
        }
        red[part][cc] = g;
        __syncthreads();
        if (tid < C) {
            float g2 = 0.f;
            #pragma unroll
            for (int p = 0; p < 16; ++p) g2 += red[p][tid];
            logitArr[tid] = simArr[tid] + sigmoidf_(g2 + b2[tid]);
        }
        __syncthreads();
        if (tid == 0) {
            float mx = logitArr[0]; int am = 0;
            #pragma unroll
            for (int cj = 1; cj < C; ++cj)
                if (logitArr[cj] > mx) { mx = logitArr[cj]; am = cj; }
            float se = 0.f;
            #pragma unroll
            for (int cj = 0; cj < C; ++cj) se += expf(logitArr[cj] - mx);
            idx[t] = am;
            wgt[t] = 1.f / se;          // mask * softmax at the argmax
            atomicAdd(&counts[am], 1);
        }
        __syncthreads();
    }
}

// ---------------------------------------------------------------------------
// scan: 16-wide exclusive prefix sum
// ---------------------------------------------------------------------------
__global__ void scan_kernel(const int* __restrict__ counts, int* __restrict__ offs,
                            int* __restrict__ cursor) {
    if (threadIdx.x == 0) {
        int s = 0;
        for (int c = 0; c < C; ++c) { offs[c] = s; cursor[c] = s; s += counts[c]; }
    }
}

// ---------------------------------------------------------------------------
// scatter: token -> per-column list
// ---------------------------------------------------------------------------
__global__ void scatter_kernel(const int* __restrict__ idx, int* __restrict__ cursor,
                               int* __restrict__ order) {
    const int t = blockIdx.x * 256 + threadIdx.x;
    const int c = idx[t];
    const int p = atomicAdd(&cursor[c], 1);
    order[p] = t;
}

// ---------------------------------------------------------------------------
// column: per-column grouped GEMM, 16 tokens per block
//   act = gelu(x @ Wc[c] + bc[c]) * w ;  y = act @ pw[c] + pb + x
// ---------------------------------------------------------------------------
__global__ __launch_bounds__(256) void column_kernel(
        const float* __restrict__ x, const float* __restrict__ Wc,
        const float* __restrict__ bc, const float* __restrict__ pw,
        const float* __restrict__ pb, const int* __restrict__ counts,
        const int* __restrict__ offs, const int* __restrict__ order,
        const float* __restrict__ wgt, float* __restrict__ out) {
    __shared__ float xs[32][16];     // x chunk, transposed [d][t]
    __shared__ float wl[32][256];    // W chunk [d][n]
    __shared__ float act[256][20];   // [n][t], stride 20 (16B-aligned, bank-spread)
    __shared__ int   tokl[16];
    __shared__ float wgl[16];
    const int c = blockIdx.y;
    const int cnt = counts[c];
    const int start = blockIdx.x * 16;
    if (start >= cnt) return;
    const int nt = min(16, cnt - start);
    const int tid = threadIdx.x;
    if (tid < 16) {
        const int i = tid < nt ? tid : 0;
        const int t = order[offs[c] + start + i];
        tokl[tid] = t;
        wgl[tid] = wgt[t];
    }
    __syncthreads();
    // ---- GEMM1: acc1[t][n] over K=1024 in BK=32 chunks ----
    const int tt = tid >> 6;         // token quad (0..3)
    const int nq = tid & 63;         // n quad (0..63)
    float acc1[4][4] = {};
    const size_t wbase = (size_t)c * D * N;
    for (int kk = 0; kk < D; kk += 32) {
        if (tid < 128) {
            const int t = tid & 15, dq = tid >> 4;   // dq 0..7
            const float4 v = *(const float4*)&x[(size_t)tokl[t] * D + kk + dq * 4];
            xs[dq * 4 + 0][t] = v.x; xs[dq * 4 + 1][t] = v.y;
            xs[dq * 4 + 2][t] = v.z; xs[dq * 4 + 3][t] = v.w;
        }
        {
            const int r = tid >> 3, q = tid & 7;
            #pragma unroll
            for (int h = 0; h < 8; ++h) {
                const int col = (q + 8 * h) * 4;
                *(float4*)&wl[r][col] =
                    *(const float4*)&Wc[wbase + (size_t)(kk + r) * N + col];
            }
        }
        __syncthreads();
        #pragma unroll
        for (int d = 0; d < 32; ++d) {
            const float4 a4 = *(const float4*)&xs[d][tt * 4];
            const float4 b4 = *(const float4*)&wl[d][nq * 4];
            const float av[4] = {a4.x, a4.y, a4.z, a4.w};
            const float bv[4] = {b4.x, b4.y, b4.z, b4.w};
            #pragma unroll
            for (int i = 0; i < 4; ++i)
                #pragma unroll
                for (int j = 0; j < 4; ++j)
                    acc1[i][j] = fmaf(av[i], bv[j], acc1[i][j]);
        }
        __syncthreads();
    }
    // ---- act = gelu(acc1 + bc) * w  -> LDS [n][t] ----
    #pragma unroll
    for (int j = 0; j < 4; ++j) {
        const int n = nq * 4 + j;
        const float bb = bc[c * N + n];
        #pragma unroll
        for (int i = 0; i < 4; ++i) {
            const int t = tt * 4 + i;
            act[n][t] = gelu_exact(acc1[i][j] + bb) * wgl[t];
        }
    }
    __syncthreads();
    // ---- GEMM2: y[t][d0..d0+3] = sum_n act[n][t] * pw[c*N+n][d] ----
    const int d0 = tid * 4;
    float4 acc2[16];
    #pragma unroll
    for (int t = 0; t < 16; ++t) acc2[t] = make_float4(0.f, 0.f, 0.f, 0.f);
    const size_t pwbase = (size_t)c * N * D;
    for (int n = 0; n < N; ++n) {
        const float4 p4 = *(const float4*)&pw[pwbase + (size_t)n * D + d0];
        #pragma unroll
        for (int tq = 0; tq < 4; ++tq) {
            const float4 a4 = *(const float4*)&act[n][tq * 4];
            const float av[4] = {a4.x, a4.y, a4.z, a4.w};
            #pragma unroll
            for (int i = 0; i < 4; ++i) {
                float4& A = acc2[tq * 4 + i];
                A.x = fmaf(av[i], p4.x, A.x);
                A.y = fmaf(av[i], p4.y, A.y);
                A.z = fmaf(av[i], p4.z, A.z);
                A.w = fmaf(av[i], p4.w, A.w);
            }
        }
    }
    const float4 pb4 = *(const float4*)&pb[d0];
    for (int t = 0; t < nt; ++t) {
        const size_t row = (size_t)tokl[t] * D;
        const float4 xv = *(const float4*)&x[row + d0];
        float4 o;
        o.x = acc2[t].x + pb4.x + xv.x;
        o.y = acc2[t].y + pb4.y + xv.y;
        o.z = acc2[t].z + pb4.z + xv.z;
        o.w = acc2[t].w + pb4.w + xv.w;
        *(float4*)&out[row + d0] = o;
    }
}

// ---------------------------------------------------------------------------
// layernorm, in-place on out
// ---------------------------------------------------------------------------
__global__ __launch_bounds__(256) void ln_kernel(float* __restrict__ out,
        const float* __restrict__ g, const float* __restrict__ b) {
    __shared__ float wr[4], wr2[4];
    const int t = blockIdx.x, tid = threadIdx.x;
    const float4 v = *(const float4*)&out[(size_t)t * D + tid * 4];
    float s = v.x + v.y + v.z + v.w;
    float s2 = v.x * v.x + v.y * v.y + v.z * v.z + v.w * v.w;
    for (int off = 32; off; off >>= 1) { s += __shfl_xor(s, off); s2 += __shfl_xor(s2, off); }
    if ((tid & 63) == 0) { wr[tid >> 6] = s; wr2[tid >> 6] = s2; }
    __syncthreads();
    const float sum = wr[0] + wr[1] + wr[2] + wr[3];
    const float sum2 = wr2[0] + wr2[1] + wr2[2] + wr2[3];
    const float mu = sum * (1.f / D);
    const float var = sum2 * (1.f / D) - mu * mu;
    const float inv = rsqrtf(var + 1e-5f);
    const float4 g4 = *(const float4*)&g[tid * 4];
    const float4 b4 = *(const float4*)&b[tid * 4];
    float4 o;
    o.x = (v.x - mu) * inv * g4.x + b4.x;
    o.y = (v.y - mu) * inv * g4.y + b4.y;
    o.z = (v.z - mu) * inv * g4.z + b4.z;
    o.w = (v.w - mu) * inv * g4.w + b4.w;
    *(float4*)&out[(size_t)t * D + tid * 4] = o;
}

// ---------------------------------------------------------------------------
extern "C" void kernel_launch(void* const* d_in, const int* in_sizes, int n_in,
                              void* d_out, int out_size, void* d_ws, size_t ws_size,
                              hipStream_t stream) {
    const float* x       = (const float*)d_in[0];
    const float* col_emb = (const float*)d_in[1];
    const float* gate_w1 = (const float*)d_in[2];
    const float* gate_b1 = (const float*)d_in[3];
    const float* gate_w2 = (const float*)d_in[4];
    const float* gate_b2 = (const float*)d_in[5];
    const float* W_cols  = (const float*)d_in[6];
    const float* b_cols  = (const float*)d_in[7];
    const float* proj_w  = (const float*)d_in[8];
    const float* proj_b  = (const float*)d_in[9];
    const float* ln_g    = (const float*)d_in[10];
    const float* ln_b    = (const float*)d_in[11];
    float* out = (float*)d_out;

    char* w = (char*)d_ws;
    float* H      = (float*)w;  w += (size_t)TOK * DH * 4;
    float* wgt    = (float*)w;  w += TOK * 4;
    float* cnorm  = (float*)w;  w += 64;
    int*   idx    = (int*)w;    w += TOK * 4;
    int*   order  = (int*)w;    w += TOK * 4;
    int*   counts = (int*)w;    w += 64;
    int*   offs   = (int*)w;    w += 64;
    int*   cursor = (int*)w;    w += 64;

    hipLaunchKernelGGL(prep_kernel, dim3(1), dim3(256), 0, stream,
                       col_emb, cnorm, counts, cursor);
    hipLaunchKernelGGL(gate_gemm_kernel, dim3(TOK / 64, DH / 64), dim3(256), 0, stream,
                       x, gate_w1, gate_b1, H);
    hipLaunchKernelGGL(route_kernel, dim3(TOK / 16), dim3(256), 0, stream,
                       x, H, col_emb, cnorm, gate_w2, gate_b2, idx, wgt, counts);
    hipLaunchKernelGGL(scan_kernel, dim3(1), dim3(64), 0, stream, counts, offs, cursor);
    hipLaunchKernelGGL(scatter_kernel, dim3(TOK / 256), dim3(256), 0, stream,
                       idx, cursor, order);
    hipLaunchKernelGGL(column_kernel, dim3(TOK / 16, C), dim3(256), 0, stream,
                       x, W_cols, b_cols, proj_w, proj_b, counts, offs, order, wgt, out);
    hipLaunchKernelGGL(ln_kernel, dim3(TOK), dim3(256), 0, stream, out, ln_g, ln_b);
}

// Round 2
// 312.070 us; speedup vs baseline: 1.8009x; 1.8009x over previous
//
#include <hip/hip_runtime.h>
#include <hip/hip_bf16.h>
#include <math.h>

#define D    1024
#define C    16
#define N    256
#define TOK  8192   // B*S
#define DH   512    // D/2

using bf16x8 = __attribute__((ext_vector_type(8))) short;
using f32x4  = __attribute__((ext_vector_type(4))) float;

__device__ __forceinline__ float gelu_exact(float v) {
    return 0.5f * v * (1.0f + erff(v * 0.70710678118654752440f));
}
__device__ __forceinline__ float sigmoidf_(float z) {
    return 1.0f / (1.0f + expf(-z));
}
__device__ __forceinline__ short f2bf(float f) {          // RNE f32->bf16
    unsigned u = __float_as_uint(f);
    unsigned r = u + 0x7FFF + ((u >> 16) & 1);
    return (short)(r >> 16);
}
__device__ __forceinline__ float bf2f(short s) {
    return __uint_as_float(((unsigned)(unsigned short)s) << 16);
}

// ---------------------------------------------------------------------------
// prep: col_emb norms + zero routing counters
// ---------------------------------------------------------------------------
__global__ void prep_kernel(const float* __restrict__ col_emb, float* __restrict__ cnorm,
                            int* __restrict__ counts, int* __restrict__ cursor) {
    const int tid = threadIdx.x;              // 256
    const int c = tid >> 4, l = tid & 15;
    float acc = 0.f;
    for (int j = 0; j < 64; ++j) {
        float v = col_emb[c * D + l + 16 * j];
        acc += v * v;
    }
    for (int off = 8; off; off >>= 1) acc += __shfl_xor(acc, off, 16);
    if (l == 0) cnorm[c] = fmaxf(sqrtf(acc), 1e-12f);
    if (tid < C) { counts[tid] = 0; cursor[tid] = 0; }
}

// ---------------------------------------------------------------------------
// straight f32 -> bf16 convert (x)
// ---------------------------------------------------------------------------
__global__ __launch_bounds__(256) void conv_kernel(const float* __restrict__ src,
                                                   short* __restrict__ dst, int n4) {
    int i = blockIdx.x * 256 + threadIdx.x;
    const int stride = gridDim.x * 256;
    for (; i < n4; i += stride) {
        const float4 v = ((const float4*)src)[i];
        short4 o;
        o.x = f2bf(v.x); o.y = f2bf(v.y); o.z = f2bf(v.z); o.w = f2bf(v.w);
        ((short4*)dst)[i] = o;
    }
}

// ---------------------------------------------------------------------------
// transpose + convert: src f32 [R][Cc] -> dst bf16 [Cc][R]  (batched over z)
// R, Cc multiples of 64
// ---------------------------------------------------------------------------
__global__ __launch_bounds__(256) void tconv_kernel(const float* __restrict__ src0,
        short* __restrict__ dst0, int R, int Cc) {
    __shared__ float tile[64][65];
    const int tid = threadIdx.x;
    const size_t bofs = (size_t)blockIdx.z * R * Cc;
    const float* src = src0 + bofs;
    short* dst = dst0 + bofs;
    const int cBase = blockIdx.x * 64;
    const int rBase = blockIdx.y * 64;
    const int rr = tid >> 4;           // 0..15
    const int cq = (tid & 15) * 4;
    #pragma unroll
    for (int h = 0; h < 4; ++h) {
        const int r = h * 16 + rr;
        const float4 v = *(const float4*)&src[(size_t)(rBase + r) * Cc + cBase + cq];
        tile[r][cq + 0] = v.x; tile[r][cq + 1] = v.y;
        tile[r][cq + 2] = v.z; tile[r][cq + 3] = v.w;
    }
    __syncthreads();
    #pragma unroll
    for (int h = 0; h < 4; ++h) {
        const int cc = h * 16 + rr;    // output row (= src col)
        short4 o;
        o.x = f2bf(tile[cq + 0][cc]);
        o.y = f2bf(tile[cq + 1][cc]);
        o.z = f2bf(tile[cq + 2][cc]);
        o.w = f2bf(tile[cq + 3][cc]);
        *(short4*)&dst[(size_t)(cBase + cc) * R + rBase + cq] = o;
    }
}

// ---------------------------------------------------------------------------
// unified bf16 MFMA tile GEMM, 64x64 tile, BK=64, 256 threads (2x2 waves)
// MODE 0: gate   H = gelu(xb @ w1) ; A=xb rows contiguous, BT=w1T, out bf16 H
// MODE 1: col g1 act = gelu(xb[tok] @ Wc + bc)*wgt ; gathered rows, out bf16
// MODE 2: col g2 y = act @ pw + pb + x ; A=act slots, out fp32 scatter
// ---------------------------------------------------------------------------
template<int MODE>
__global__ __launch_bounds__(256) void mfma_tile(
        const short* __restrict__ Ag, const short* __restrict__ BTg,
        const float* __restrict__ bias, const float* __restrict__ x,
        const int* __restrict__ counts, const int* __restrict__ offs,
        const int* __restrict__ order, const float* __restrict__ wgt,
        short* __restrict__ outb, float* __restrict__ outf) {
    constexpr int KDIM = (MODE == 2) ? N : D;
    constexpr int KSTEPS = KDIM / 64;
    __shared__ short As[64 * 64];
    __shared__ short Bs[64 * 64];
    __shared__ int   tokl[64];
    __shared__ float wgl[64];

    const int tid = threadIdx.x;
    const int lane = tid & 63;
    const int wave = tid >> 6;
    const int wr = wave >> 1, wc = wave & 1;

    int cnt = 64, start = 0, col = 0, slotBase = 0, nt = 64;
    if (MODE >= 1) {
        col = blockIdx.z;
        cnt = counts[col];
        start = blockIdx.x * 64;
        if (start >= cnt) return;
        slotBase = offs[col] + start;
        nt = min(64, cnt - start);
        if (tid < 64) {
            const int i = tid < nt ? tid : nt - 1;
            const int t = order[offs[col] + start + i];
            tokl[tid] = t;
            if (MODE == 1) wgl[tid] = wgt[t];
        }
        __syncthreads();
    }

    // ---- staging setup: each thread stages 16B of 2 rows for A and B ----
    const int rA0 = tid >> 3;                // 0..31
    const int rA1 = rA0 + 32;                // 32..63
    const int bo  = (tid & 7) * 16;          // byte offset in 128B chunk
    const char* gA0; const char* gA1;
    if (MODE == 0) {
        const size_t m0 = (size_t)blockIdx.x * 64;
        gA0 = (const char*)Ag + (m0 + rA0) * (D * 2) + bo;
        gA1 = (const char*)Ag + (m0 + rA1) * (D * 2) + bo;
    } else if (MODE == 1) {
        gA0 = (const char*)Ag + (size_t)tokl[rA0] * (D * 2) + bo;
        gA1 = (const char*)Ag + (size_t)tokl[rA1] * (D * 2) + bo;
    } else {
        const int lastSlot = offs[col] + cnt - 1;
        const int s0 = min(slotBase + rA0, lastSlot);
        const int s1 = min(slotBase + rA1, lastSlot);
        gA0 = (const char*)Ag + (size_t)s0 * (N * 2) + bo;
        gA1 = (const char*)Ag + (size_t)s1 * (N * 2) + bo;
    }
    const size_t bRowB = KDIM * 2;
    const char* gB0; const char* gB1;
    {
        size_t bbase;
        if (MODE == 0)      bbase = (size_t)blockIdx.y * 64 * bRowB;
        else if (MODE == 1) bbase = ((size_t)col * N + blockIdx.y * 64) * bRowB;
        else                bbase = ((size_t)col * D + blockIdx.y * 64) * bRowB;
        gB0 = (const char*)BTg + bbase + (size_t)rA0 * bRowB + bo;
        gB1 = (const char*)BTg + bbase + (size_t)rA1 * bRowB + bo;
    }
    char* const wA0 = (char*)As + rA0 * 128 + (bo ^ ((rA0 & 7) << 4));
    char* const wA1 = (char*)As + rA1 * 128 + (bo ^ ((rA1 & 7) << 4));
    char* const wB0 = (char*)Bs + rA0 * 128 + (bo ^ ((rA0 & 7) << 4));
    char* const wB1 = (char*)Bs + rA1 * 128 + (bo ^ ((rA1 & 7) << 4));

    // ---- fragment read addressing ----
    const int mrow = wr * 32 + (lane & 15);
    const int nrow = wc * 32 + (lane & 15);
    const int kbB  = (lane >> 4) * 16;       // byte offset of this lane's k-chunk
    const int swm  = (mrow & 7) << 4;
    const int swn  = (nrow & 7) << 4;

    f32x4 acc[2][2] = {};
    for (int kk = 0; kk < KSTEPS; ++kk) {
        *(bf16x8*)wA0 = *(const bf16x8*)gA0;
        *(bf16x8*)wA1 = *(const bf16x8*)gA1;
        *(bf16x8*)wB0 = *(const bf16x8*)gB0;
        *(bf16x8*)wB1 = *(const bf16x8*)gB1;
        gA0 += 128; gA1 += 128; gB0 += 128; gB1 += 128;
        __syncthreads();
        #pragma unroll
        for (int ks = 0; ks < 2; ++ks) {
            bf16x8 aF[2], bF[2];
            #pragma unroll
            for (int i = 0; i < 2; ++i)
                aF[i] = *(const bf16x8*)((const char*)As + (mrow + i * 16) * 128
                                         + ((kbB + ks * 64) ^ swm));
            #pragma unroll
            for (int j = 0; j < 2; ++j)
                bF[j] = *(const bf16x8*)((const char*)Bs + (nrow + j * 16) * 128
                                         + ((kbB + ks * 64) ^ swn));
            #pragma unroll
            for (int i = 0; i < 2; ++i)
                #pragma unroll
                for (int j = 0; j < 2; ++j)
                    acc[i][j] = __builtin_amdgcn_mfma_f32_16x16x32_bf16(
                                    aF[i], bF[j], acc[i][j], 0, 0, 0);
        }
        __syncthreads();
    }

    // ---- epilogue ----
    const int crow = (lane >> 4) * 4;
    const int ccol = lane & 15;
    if (MODE == 0) {
        const int m0 = blockIdx.x * 64;
        const int n0 = blockIdx.y * 64;
        #pragma unroll
        for (int i = 0; i < 2; ++i)
            #pragma unroll
            for (int j = 0; j < 2; ++j) {
                const int n = n0 + wc * 32 + j * 16 + ccol;
                const float bb = bias[n];
                #pragma unroll
                for (int r = 0; r < 4; ++r) {
                    const int m = m0 + wr * 32 + i * 16 + crow + r;
                    outb[(size_t)m * DH + n] = f2bf(gelu_exact(acc[i][j][r] + bb));
                }
            }
    } else if (MODE == 1) {
        const int n0 = blockIdx.y * 64;
        #pragma unroll
        for (int i = 0; i < 2; ++i)
            #pragma unroll
            for (int j = 0; j < 2; ++j) {
                const int n = n0 + wc * 32 + j * 16 + ccol;
                const float bb = bias[col * N + n];
                #pragma unroll
                for (int r = 0; r < 4; ++r) {
                    const int il = wr * 32 + i * 16 + crow + r;
                    if (il < nt) {
                        const float v = gelu_exact(acc[i][j][r] + bb) * wgl[il];
                        outb[(size_t)(slotBase + il) * N + n] = f2bf(v);
                    }
                }
            }
    } else {
        const int n0 = blockIdx.y * 64;
        #pragma unroll
        for (int i = 0; i < 2; ++i)
            #pragma unroll
            for (int j = 0; j < 2; ++j) {
                const int dcol = n0 + wc * 32 + j * 16 + ccol;
                const float bb = bias[dcol];
                #pragma unroll
                for (int r = 0; r < 4; ++r) {
                    const int il = wr * 32 + i * 16 + crow + r;
                    if (il < nt) {
                        const size_t ofs = (size_t)tokl[il] * D + dcol;
                        outf[ofs] = acc[i][j][r] + bb + x[ofs];
                    }
                }
            }
    }
}

// ---------------------------------------------------------------------------
// route: logits = sim + sigmoid(H @ gate_w2 + b2); top-1 idx + softmax weight
// ---------------------------------------------------------------------------
__global__ __launch_bounds__(256) void route_kernel(
        const float* __restrict__ x, const short* __restrict__ Hb,
        const float* __restrict__ col_emb, const float* __restrict__ cnorm,
        const float* __restrict__ w2, const float* __restrict__ b2,
        int* __restrict__ idx, float* __restrict__ wgt, int* __restrict__ counts) {
    __shared__ float xl[D];
    __shared__ float hl[DH];
    __shared__ float simArr[C];
    __shared__ float red[16][17];
    __shared__ float logitArr[C];
    __shared__ float wavered[4];
    const int tid = threadIdx.x;
    const int c = tid >> 4, l16 = tid & 15;
    for (int ti = 0; ti < 16; ++ti) {
        const int t = blockIdx.x * 16 + ti;
        const float4 xv = *(const float4*)&x[(size_t)t * D + tid * 4];
        *(float4*)&xl[tid * 4] = xv;
        float ss = xv.x * xv.x + xv.y * xv.y + xv.z * xv.z + xv.w * xv.w;
        for (int off = 32; off; off >>= 1) ss += __shfl_xor(ss, off);
        if ((tid & 63) == 0) wavered[tid >> 6] = ss;
        if (tid < 128) {
            const short4 hv = *(const short4*)&Hb[(size_t)t * DH + tid * 4];
            hl[tid * 4 + 0] = bf2f(hv.x); hl[tid * 4 + 1] = bf2f(hv.y);
            hl[tid * 4 + 2] = bf2f(hv.z); hl[tid * 4 + 3] = bf2f(hv.w);
        }
        __syncthreads();
        const float xn = fmaxf(sqrtf(wavered[0] + wavered[1] + wavered[2] + wavered[3]), 1e-12f);
        float sacc = 0.f;
        for (int j = 0; j < 64; ++j) {
            const int d = l16 + 16 * j;
            sacc += xl[d] * col_emb[c * D + d];
        }
        for (int off = 8; off; off >>= 1) sacc += __shfl_xor(sacc, off, 16);
        if (l16 == 0) simArr[c] = sacc / (xn * cnorm[c]);
        const int cc = tid & 15, part = tid >> 4;
        float g = 0.f;
        for (int i = 0; i < 32; ++i) {
            const int d = part * 32 + i;
            g += hl[d] * w2[d * C + cc];
        }
        red[part][cc] = g;
        __syncthreads();
        if (tid < C) {
            float g2 = 0.f;
            #pragma unroll
            for (int p = 0; p < 16; ++p) g2 += red[p][tid];
            logitArr[tid] = simArr[tid] + sigmoidf_(g2 + b2[tid]);
        }
        __syncthreads();
        if (tid == 0) {
            float mx = logitArr[0]; int am = 0;
            #pragma unroll
            for (int cj = 1; cj < C; ++cj)
                if (logitArr[cj] > mx) { mx = logitArr[cj]; am = cj; }
            float se = 0.f;
            #pragma unroll
            for (int cj = 0; cj < C; ++cj) se += expf(logitArr[cj] - mx);
            idx[t] = am;
            wgt[t] = 1.f / se;
            atomicAdd(&counts[am], 1);
        }
        __syncthreads();
    }
}

__global__ void scan_kernel(const int* __restrict__ counts, int* __restrict__ offs,
                            int* __restrict__ cursor) {
    if (threadIdx.x == 0) {
        int s = 0;
        for (int c = 0; c < C; ++c) { offs[c] = s; cursor[c] = s; s += counts[c]; }
    }
}

__global__ void scatter_kernel(const int* __restrict__ idx, int* __restrict__ cursor,
                               int* __restrict__ order) {
    const int t = blockIdx.x * 256 + threadIdx.x;
    const int c = idx[t];
    const int p = atomicAdd(&cursor[c], 1);
    order[p] = t;
}

// ---------------------------------------------------------------------------
// layernorm, in-place on out
// ---------------------------------------------------------------------------
__global__ __launch_bounds__(256) void ln_kernel(float* __restrict__ out,
        const float* __restrict__ g, const float* __restrict__ b) {
    __shared__ float wr_[4], wr2[4];
    const int t = blockIdx.x, tid = threadIdx.x;
    const float4 v = *(const float4*)&out[(size_t)t * D + tid * 4];
    float s = v.x + v.y + v.z + v.w;
    float s2 = v.x * v.x + v.y * v.y + v.z * v.z + v.w * v.w;
    for (int off = 32; off; off >>= 1) { s += __shfl_xor(s, off); s2 += __shfl_xor(s2, off); }
    if ((tid & 63) == 0) { wr_[tid >> 6] = s; wr2[tid >> 6] = s2; }
    __syncthreads();
    const float sum = wr_[0] + wr_[1] + wr_[2] + wr_[3];
    const float sum2 = wr2[0] + wr2[1] + wr2[2] + wr2[3];
    const float mu = sum * (1.f / D);
    const float var = sum2 * (1.f / D) - mu * mu;
    const float inv = rsqrtf(var + 1e-5f);
    const float4 g4 = *(const float4*)&g[tid * 4];
    const float4 b4 = *(const float4*)&b[tid * 4];
    float4 o;
    o.x = (v.x - mu) * inv * g4.x + b4.x;
    o.y = (v.y - mu) * inv * g4.y + b4.y;
    o.z = (v.z - mu) * inv * g4.z + b4.z;
    o.w = (v.w - mu) * inv * g4.w + b4.w;
    *(float4*)&out[(size_t)t * D + tid * 4] = o;
}

// ---------------------------------------------------------------------------
extern "C" void kernel_launch(void* const* d_in, const int* in_sizes, int n_in,
                              void* d_out, int out_size, void* d_ws, size_t ws_size,
                              hipStream_t stream) {
    const float* x       = (const float*)d_in[0];
    const float* col_emb = (const float*)d_in[1];
    const float* gate_w1 = (const float*)d_in[2];
    const float* gate_b1 = (const float*)d_in[3];
    const float* gate_w2 = (const float*)d_in[4];
    const float* gate_b2 = (const float*)d_in[5];
    const float* W_cols  = (const float*)d_in[6];
    const float* b_cols  = (const float*)d_in[7];
    const float* proj_w  = (const float*)d_in[8];
    const float* proj_b  = (const float*)d_in[9];
    const float* ln_g    = (const float*)d_in[10];
    const float* ln_b    = (const float*)d_in[11];
    float* out = (float*)d_out;

    char* w = (char*)d_ws;
    short* xb    = (short*)w;  w += (size_t)TOK * D * 2;           // 16 MB
    short* Hb    = (short*)w;  w += (size_t)TOK * DH * 2;          //  8 MB
    short* actb  = (short*)w;  w += (size_t)TOK * N * 2 + 65536;   //  4 MB + slack
    short* w1T   = (short*)w;  w += (size_t)DH * D * 2;            //  1 MB
    short* WcT   = (short*)w;  w += (size_t)C * N * D * 2;         //  8 MB
    short* pwT   = (short*)w;  w += (size_t)C * D * N * 2;         //  8 MB
    float* wgt   = (float*)w;  w += TOK * 4;
    float* cnorm = (float*)w;  w += 64;
    int*   idx   = (int*)w;    w += TOK * 4;
    int*   order = (int*)w;    w += TOK * 4;
    int*   counts= (int*)w;    w += 64;
    int*   offs  = (int*)w;    w += 64;
    int*   cursor= (int*)w;    w += 64;

    hipLaunchKernelGGL(prep_kernel, dim3(1), dim3(256), 0, stream,
                       col_emb, cnorm, counts, cursor);
    hipLaunchKernelGGL(conv_kernel, dim3(2048), dim3(256), 0, stream,
                       x, xb, TOK * D / 4);
    hipLaunchKernelGGL(tconv_kernel, dim3(DH / 64, D / 64, 1), dim3(256), 0, stream,
                       gate_w1, w1T, D, DH);
    hipLaunchKernelGGL(tconv_kernel, dim3(N / 64, D / 64, C), dim3(256), 0, stream,
                       W_cols, WcT, D, N);
    hipLaunchKernelGGL(tconv_kernel, dim3(D / 64, N / 64, C), dim3(256), 0, stream,
                       proj_w, pwT, N, D);
    // gate GEMM (bf16 MFMA) -> Hb
    hipLaunchKernelGGL((mfma_tile<0>), dim3(TOK / 64, DH / 64, 1), dim3(256), 0, stream,
                       xb, w1T, gate_b1, nullptr, nullptr, nullptr, nullptr, nullptr,
                       Hb, nullptr);
    hipLaunchKernelGGL(route_kernel, dim3(TOK / 16), dim3(256), 0, stream,
                       x, Hb, col_emb, cnorm, gate_w2, gate_b2, idx, wgt, counts);
    hipLaunchKernelGGL(scan_kernel, dim3(1), dim3(64), 0, stream, counts, offs, cursor);
    hipLaunchKernelGGL(scatter_kernel, dim3(TOK / 256), dim3(256), 0, stream,
                       idx, cursor, order);
    // column GEMM1 (grouped, bf16 MFMA) -> actb
    hipLaunchKernelGGL((mfma_tile<1>), dim3(TOK / 64, N / 64, C), dim3(256), 0, stream,
                       xb, WcT, b_cols, nullptr, counts, offs, order, wgt,
                       actb, nullptr);
    // column GEMM2 (grouped, bf16 MFMA) -> out (+bias+residual)
    hipLaunchKernelGGL((mfma_tile<2>), dim3(TOK / 64, D / 64, C), dim3(256), 0, stream,
                       actb, pwT, proj_b, x, counts, offs, order, wgt,
                       nullptr, out);
    hipLaunchKernelGGL(ln_kernel, dim3(TOK), dim3(256), 0, stream, out, ln_g, ln_b);
}